// Round 6
// baseline (161.116 us; speedup 1.0000x reference)
//
#include <hip/hip_runtime.h>

#define NB    256   // neighbors
#define DIN   64
#define LATD  128
#define ECD   32

typedef __attribute__((ext_vector_type(8))) __bf16 bf16x8;
typedef __attribute__((ext_vector_type(2))) __bf16 bf16x2;
typedef __attribute__((ext_vector_type(4))) float f32x4;

#define XS_STRIDE 72   // ws row stride for WcT/WfT (bf16 elems)
#define EC_STRIDE 40   // 32 data + 8 pad (LDS bank spread)
#define WA_STRIDE 40

// d_ws layout
#define WS_WC  0                     // WcT  [32][72]  bf16
#define WS_WF  (32 * 72)             // WfT  [128][72] bf16
#define WS_WA  (32 * 72 + 128 * 72)  // WaTm [128][40] bf16, pre-scaled by log2(e)
#define WS_WLT_BYTES 33280           // WlT [128][128] fp32 (row c holds Wl[:,c])

#define LOG2E 1.44269504f

#define MFMA(a, b, c) __builtin_amdgcn_mfma_f32_16x16x32_bf16((a), (b), (c), 0, 0, 0)

__device__ __forceinline__ unsigned short f2bf(float f) {
    unsigned u = __builtin_bit_cast(unsigned, f);
    u += 0x7fffu + ((u >> 16) & 1u);   // RNE
    return (unsigned short)(u >> 16);
}

__device__ __forceinline__ bf16x2 cvt2(float a, float b) {
#if defined(__has_builtin) && __has_builtin(__builtin_amdgcn_cvt_pk_bf16_f32)
    return __builtin_amdgcn_cvt_pk_bf16_f32(a, b);
#else
    union { unsigned short u[2]; bf16x2 v; } r;
    r.u[0] = f2bf(a); r.u[1] = f2bf(b);
    return r.v;
#endif
}

__device__ __forceinline__ bf16x8 pack8(float4 a, float4 b) {
    union { bf16x2 h[4]; bf16x8 v; } r;
    r.h[0] = cvt2(a.x, a.y); r.h[1] = cvt2(a.z, a.w);
    r.h[2] = cvt2(b.x, b.y); r.h[3] = cvt2(b.z, b.w);
    return r.v;
}

// Pre-transpose weights: bf16 B-frag layouts for Wc/Wf/Wa (Wa scaled by log2e),
// plus fp32 transposed Wl for the tail matvec.
__global__ __launch_bounds__(256) void prep_kernel(
    const float* __restrict__ Wc, const float* __restrict__ Wf,
    const float* __restrict__ Wa, const float* __restrict__ Wl,
    unsigned short* __restrict__ ws)
{
    int t = blockIdx.x * blockDim.x + threadIdx.x;
    int stride = gridDim.x * blockDim.x;
    for (int i = t; i < 32 * 64; i += stride) {
        int n = i >> 6, k = i & 63;
        ws[WS_WC + n * XS_STRIDE + k] = f2bf(Wc[k * ECD + n]);
    }
    for (int i = t; i < 128 * 64; i += stride) {
        int n = i >> 6, k = i & 63;
        ws[WS_WF + n * XS_STRIDE + k] = f2bf(Wf[k * LATD + n]);
    }
    for (int i = t; i < 128 * 32; i += stride) {
        int n = i >> 5, k = i & 31;
        ws[WS_WA + n * WA_STRIDE + k] = f2bf(Wa[(ECD + k) * LATD + n] * LOG2E);
    }
    float* wlt = reinterpret_cast<float*>(reinterpret_cast<char*>(ws) + WS_WLT_BYTES);
    for (int i = t; i < 128 * 128; i += stride) {
        int c = i >> 7, k = i & 127;
        wlt[c * 128 + k] = Wl[k * LATD + c];
    }
}

struct SmemT {
    unsigned short ecs[NB * EC_STRIDE];  // 20480 B
    float aggnum[8][LATD];
    float aggden[8][LATD];
    float aggfull[LATD];
    float wlpart[4][LATD];
};

// Full per-b pipeline after X is already in A-fragments. 3 barriers.
__device__ __forceinline__ void process_b(
    int b, int w, int lane, int l15, int q, int tid,
    const bf16x8 xfrag[2][2], const bf16x8 wcfrag[2][2],
    float bc0, float bc1, const float bfl8[8],
    const unsigned short* __restrict__ ws, const float* __restrict__ blv,
    float* __restrict__ out, SmemT& sm)
{
    // enc_comm = relu(X*Wc + bc) -> ecs bf16 (wave-private rows, no barrier)
    #pragma unroll
    for (int t = 0; t < 2; ++t) {
        f32x4 a0 = {bc0, bc0, bc0, bc0};   // bias via C-operand (col-uniform)
        f32x4 a1 = {bc1, bc1, bc1, bc1};
        #pragma unroll
        for (int ks = 0; ks < 2; ++ks) {
            a0 = MFMA(xfrag[t][ks], wcfrag[ks][0], a0);
            a1 = MFMA(xfrag[t][ks], wcfrag[ks][1], a1);
        }
        int rowA = w * 32 + t * 16;
        #pragma unroll
        for (int r = 0; r < 4; ++r) {
            int row = rowA + q * 4 + r;   // C/D: row = quad*4 + reg
            union { bf16x2 v; unsigned short u[2]; } pr;
            pr.v = cvt2(fmaxf(a0[r], 0.f), fmaxf(a1[r], 0.f));
            sm.ecs[row * EC_STRIDE + l15]      = pr.u[0];
            sm.ecs[row * EC_STRIDE + 16 + l15] = pr.u[1];
        }
    }

    bf16x8 ecfrag[2];
    #pragma unroll
    for (int t = 0; t < 2; ++t)
        ecfrag[t] = *reinterpret_cast<const bf16x8*>(
            &sm.ecs[(w * 32 + t * 16 + l15) * EC_STRIDE + q * 8]);

    // fused g-loop: enc_feature + logits + unnormalized softmax partials
    for (int g = 0; g < 8; ++g) {
        bf16x8 wf0 = *reinterpret_cast<const bf16x8*>(
            &ws[WS_WF + (g * 16 + l15) * XS_STRIDE + q * 8]);
        bf16x8 wf1 = *reinterpret_cast<const bf16x8*>(
            &ws[WS_WF + (g * 16 + l15) * XS_STRIDE + 32 + q * 8]);
        bf16x8 wag = *reinterpret_cast<const bf16x8*>(
            &ws[WS_WA + (g * 16 + l15) * WA_STRIDE + q * 8]);
        float bfl = bfl8[g];

        float num = 0.f, den = 0.f;
        #pragma unroll
        for (int t = 0; t < 2; ++t) {
            f32x4 z = {bfl, bfl, bfl, bfl};   // bf bias via C-operand
            z = MFMA(xfrag[t][0], wf0, z);
            f32x4 ef = MFMA(xfrag[t][1], wf1, z);
            f32x4 z2 = {0.f, 0.f, 0.f, 0.f};
            f32x4 lg = MFMA(ecfrag[t], wag, z2);
            #pragma unroll
            for (int r = 0; r < 4; ++r) {
                float e = fmaxf(ef[r], 0.f);
                float p = exp2f(lg[r]);       // log2e pre-folded into Wa
                num += p * e;
                den += p;
            }
        }
        num += __shfl_xor(num, 16, 64); num += __shfl_xor(num, 32, 64);
        den += __shfl_xor(den, 16, 64); den += __shfl_xor(den, 32, 64);
        if (lane < 16) {
            sm.aggnum[w][g * 16 + lane] = num;
            sm.aggden[w][g * 16 + lane] = den;
        }
    }
    __syncthreads();

    // aggregated[k] = sum(num)/sum(den)
    if (tid < 128) {
        float num = 0.f, den = 0.f;
        #pragma unroll
        for (int i = 0; i < 8; ++i) { num += sm.aggnum[i][tid]; den += sm.aggden[i][tid]; }
        sm.aggfull[tid] = num / den;
    }
    __syncthreads();

    // out = relu(agg @ Wl + bl): transposed fp32 Wl, 4-way k-split
    {
        const float* wlt = reinterpret_cast<const float*>(
            reinterpret_cast<const char*>(ws) + WS_WLT_BYTES);
        int c = tid & 127, h = tid >> 7;
        const float* wr = wlt + c * 128 + h * 32;
        float acc = 0.f;
        #pragma unroll
        for (int j = 0; j < 8; ++j) {
            float4 v = *reinterpret_cast<const float4*>(wr + j * 4);
            int k = h * 32 + j * 4;
            acc += sm.aggfull[k] * v.x + sm.aggfull[k + 1] * v.y +
                   sm.aggfull[k + 2] * v.z + sm.aggfull[k + 3] * v.w;
        }
        sm.wlpart[h][c] = acc;
    }
    __syncthreads();
    if (tid < 128)
        out[(size_t)b * LATD + tid] =
            fmaxf(sm.wlpart[0][tid] + sm.wlpart[1][tid] + sm.wlpart[2][tid] +
                  sm.wlpart[3][tid] + blv[tid], 0.f);
}

// 512 blocks x 512 threads; each block pipelines TWO batch elements:
// b1's X loads are issued before b0's compute, so b0's whole pipeline hides
// b1's memory latency; fixed costs (Wc frags, biases, WlT) paid once per pair.
// Algebra: self_rep/mean_rep/ba are n-invariant -> cancel in softmax(axis=n);
// att = softmax_n(enc_comm @ Wa[32:64]); max-subtraction dropped (logits O(+-3)).
__global__ __launch_bounds__(512, 4) void arm_main(
    const float* __restrict__ xg,   // neighbor [B][256][64]
    const float* __restrict__ bcv,  // bc [32]
    const float* __restrict__ bfv,  // bf [128]
    const float* __restrict__ blv,  // bl [128]
    const unsigned short* __restrict__ ws,
    float* __restrict__ out)        // [B][128]
{
    __shared__ SmemT sm;

    const int tid  = threadIdx.x;
    const int lane = tid & 63;
    const int w    = tid >> 6;   // wave 0..7, owns rows 32w..32w+31 (2 m-tiles)
    const int l15  = lane & 15;
    const int q    = lane >> 4;
    const int b0   = blockIdx.x * 2;

    // A-frag: row = lane&15 (within tile), k = quad*8 + j -> 8 contiguous floats.
    const float* xb0 = xg + (size_t)b0 * NB * DIN;
    const float* xb1 = xb0 + NB * DIN;

    // ---- issue b0 loads ----
    float4 r0[2][4];
    #pragma unroll
    for (int t = 0; t < 2; ++t) {
        const float* p = xb0 + (w * 32 + t * 16 + l15) * DIN + q * 8;
        r0[t][0] = *reinterpret_cast<const float4*>(p);
        r0[t][1] = *reinterpret_cast<const float4*>(p + 4);
        r0[t][2] = *reinterpret_cast<const float4*>(p + 32);
        r0[t][3] = *reinterpret_cast<const float4*>(p + 36);
    }
    // ---- issue b1 loads (held across b0's entire pipeline) ----
    float4 r1[2][4];
    #pragma unroll
    for (int t = 0; t < 2; ++t) {
        const float* p = xb1 + (w * 32 + t * 16 + l15) * DIN + q * 8;
        r1[t][0] = *reinterpret_cast<const float4*>(p);
        r1[t][1] = *reinterpret_cast<const float4*>(p + 4);
        r1[t][2] = *reinterpret_cast<const float4*>(p + 32);
        r1[t][3] = *reinterpret_cast<const float4*>(p + 36);
    }

    // ---- hoisted block-invariant state (paid once per pair) ----
    bf16x8 wcfrag[2][2];
    #pragma unroll
    for (int ks = 0; ks < 2; ++ks)
        #pragma unroll
        for (int nb = 0; nb < 2; ++nb)
            wcfrag[ks][nb] = *reinterpret_cast<const bf16x8*>(
                &ws[WS_WC + (nb * 16 + l15) * XS_STRIDE + ks * 32 + q * 8]);
    float bc0 = bcv[l15], bc1 = bcv[16 + l15];
    float bfl8[8];
    #pragma unroll
    for (int g = 0; g < 8; ++g) bfl8[g] = bfv[g * 16 + l15];

    // ---- b0 ----
    {
        bf16x8 xfrag[2][2];
        #pragma unroll
        for (int t = 0; t < 2; ++t) {
            xfrag[t][0] = pack8(r0[t][0], r0[t][1]);
            xfrag[t][1] = pack8(r0[t][2], r0[t][3]);
        }
        process_b(b0, w, lane, l15, q, tid, xfrag, wcfrag, bc0, bc1, bfl8,
                  ws, blv, out, sm);
    }
    // ---- b1 (loads landed long ago) ----
    {
        bf16x8 xfrag[2][2];
        #pragma unroll
        for (int t = 0; t < 2; ++t) {
            xfrag[t][0] = pack8(r1[t][0], r1[t][1]);
            xfrag[t][1] = pack8(r1[t][2], r1[t][3]);
        }
        process_b(b0 + 1, w, lane, l15, q, tid, xfrag, wcfrag, bc0, bc1, bfl8,
                  ws, blv, out, sm);
    }
}

extern "C" void kernel_launch(void* const* d_in, const int* in_sizes, int n_in,
                              void* d_out, int out_size, void* d_ws, size_t ws_size,
                              hipStream_t stream)
{
    const float* xg  = (const float*)d_in[1];
    const float* wc  = (const float*)d_in[2];
    const float* bc_ = (const float*)d_in[3];
    const float* wf  = (const float*)d_in[4];
    const float* bf_ = (const float*)d_in[5];
    const float* wa  = (const float*)d_in[6];
    const float* wl  = (const float*)d_in[8];
    const float* bl_ = (const float*)d_in[9];
    unsigned short* wsp = (unsigned short*)d_ws;   // needs 98,816 B of ws
    float* out = (float*)d_out;

    prep_kernel<<<16, 256, 0, stream>>>(wc, wf, wa, wl, wsp);
    arm_main<<<512, 512, 0, stream>>>(xg, bc_, bf_, bl_, wsp, out);
}

// Round 7
// 142.656 us; speedup vs baseline: 1.1294x; 1.1294x over previous
//
#include <hip/hip_runtime.h>

#define NB    256   // neighbors
#define DIN   64
#define LATD  128
#define ECD   32

typedef __attribute__((ext_vector_type(8))) __bf16 bf16x8;
typedef __attribute__((ext_vector_type(2))) __bf16 bf16x2;
typedef __attribute__((ext_vector_type(4))) float f32x4;

#define XS_STRIDE 72   // ws row stride for WcT/WfT (bf16 elems)
#define EC_STRIDE 40   // LDS enc_comm row stride (shorts)
#define WA_STRIDE 40

// d_ws layout
#define WS_WC  0                     // WcT  [32][72]  bf16
#define WS_WF  (32 * 72)             // WfT  [128][72] bf16
#define WS_WA  (32 * 72 + 128 * 72)  // WaTm [128][40] bf16, pre-scaled by log2(e)
#define WS_WLT_BYTES   33280         // WlT [128][128] fp32 (row c holds Wl[:,c])
#define WS_ND_BYTES    (33280 + 65536)  // numden [B][256] fp32: [0:128]=num,[128:256]=den
#define WS_TOTAL_BYTES (WS_ND_BYTES + 1024 * 256 * 4)

#define LOG2E 1.44269504f

#define MFMA(a, b, c) __builtin_amdgcn_mfma_f32_16x16x32_bf16((a), (b), (c), 0, 0, 0)

__device__ __forceinline__ unsigned short f2bf(float f) {
    unsigned u = __builtin_bit_cast(unsigned, f);
    u += 0x7fffu + ((u >> 16) & 1u);   // RNE
    return (unsigned short)(u >> 16);
}

__device__ __forceinline__ bf16x2 cvt2(float a, float b) {
#if defined(__has_builtin) && __has_builtin(__builtin_amdgcn_cvt_pk_bf16_f32)
    return __builtin_amdgcn_cvt_pk_bf16_f32(a, b);
#else
    union { unsigned short u[2]; bf16x2 v; } r;
    r.u[0] = f2bf(a); r.u[1] = f2bf(b);
    return r.v;
#endif
}

__device__ __forceinline__ bf16x8 pack8(float4 a, float4 b) {
    union { bf16x2 h[4]; bf16x8 v; } r;
    r.h[0] = cvt2(a.x, a.y); r.h[1] = cvt2(a.z, a.w);
    r.h[2] = cvt2(b.x, b.y); r.h[3] = cvt2(b.z, b.w);
    return r.v;
}

// Pre-transpose weights: bf16 B-frag layouts for Wc/Wf/Wa (Wa scaled by log2e),
// plus fp32 transposed Wl for the finish matvec.
__global__ __launch_bounds__(256) void prep_kernel(
    const float* __restrict__ Wc, const float* __restrict__ Wf,
    const float* __restrict__ Wa, const float* __restrict__ Wl,
    unsigned short* __restrict__ ws)
{
    int t = blockIdx.x * blockDim.x + threadIdx.x;
    int stride = gridDim.x * blockDim.x;
    for (int i = t; i < 32 * 64; i += stride) {
        int n = i >> 6, k = i & 63;
        ws[WS_WC + n * XS_STRIDE + k] = f2bf(Wc[k * ECD + n]);
    }
    for (int i = t; i < 128 * 64; i += stride) {
        int n = i >> 6, k = i & 63;
        ws[WS_WF + n * XS_STRIDE + k] = f2bf(Wf[k * LATD + n]);
    }
    for (int i = t; i < 128 * 32; i += stride) {
        int n = i >> 5, k = i & 31;
        ws[WS_WA + n * WA_STRIDE + k] = f2bf(Wa[(ECD + k) * LATD + n] * LOG2E);
    }
    float* wlt = reinterpret_cast<float*>(reinterpret_cast<char*>(ws) + WS_WLT_BYTES);
    for (int i = t; i < 128 * 128; i += stride) {
        int c = i >> 7, k = i & 127;
        wlt[c * 128 + k] = Wl[k * LATD + c];
    }
}

// 4096 blocks = (b, 64-row n-chunk); 256 threads = 4 waves, wave owns 16 rows
// (one 16x16 m-tile). Streams X once, fuses enc_comm -> enc_feature/logits ->
// exp2 -> num/den partials over its rows, then atomicAdds into ws numden[b].
// Algebra: self_rep/mean_rep/ba are n-invariant -> cancel in softmax(axis=n);
// att = softmax_n(enc_comm @ Wa[32:64]); max-subtraction dropped (logits O(+-3));
// log2(e) pre-folded into Wa; biases enter via the MFMA C-operand.
__global__ __launch_bounds__(256, 4) void encode_kernel(
    const float* __restrict__ xg,   // neighbor [B][256][64]
    const float* __restrict__ bcv,  // bc [32]
    const float* __restrict__ bfv,  // bf [128]
    const unsigned short* __restrict__ ws,
    float* __restrict__ numden)     // [B][256]: num[128] | den[128]
{
    __shared__ unsigned short ecs[4 * 16 * EC_STRIDE];  // 5120 B, per-wave areas
    __shared__ float aggnum[4][LATD];                   // 2048 B
    __shared__ float aggden[4][LATD];                   // 2048 B

    const int blk  = blockIdx.x;
    const int b    = blk >> 2;
    const int chnk = blk & 3;          // 64-row chunk within the 256 neighbors
    const int tid  = threadIdx.x;
    const int lane = tid & 63;
    const int w    = tid >> 6;
    const int l15  = lane & 15;
    const int q    = lane >> 4;

    // ---- X rows -> A-fragments (row = lane&15, k = quad*8+j) ----
    const float* p = xg + ((size_t)b * NB + chnk * 64 + w * 16 + l15) * DIN + q * 8;
    float4 a0 = *reinterpret_cast<const float4*>(p);
    float4 a1 = *reinterpret_cast<const float4*>(p + 4);
    float4 a2 = *reinterpret_cast<const float4*>(p + 32);
    float4 a3 = *reinterpret_cast<const float4*>(p + 36);
    bf16x8 xf0 = pack8(a0, a1);
    bf16x8 xf1 = pack8(a2, a3);

    // ---- enc_comm = relu(X*Wc + bc) -> wave-private LDS area ----
    {
        float bc0 = bcv[l15], bc1 = bcv[16 + l15];
        f32x4 e0 = {bc0, bc0, bc0, bc0};
        f32x4 e1 = {bc1, bc1, bc1, bc1};
        #pragma unroll
        for (int ks = 0; ks < 2; ++ks) {
            bf16x8 wc0 = *reinterpret_cast<const bf16x8*>(
                &ws[WS_WC + l15 * XS_STRIDE + ks * 32 + q * 8]);
            bf16x8 wc1 = *reinterpret_cast<const bf16x8*>(
                &ws[WS_WC + (16 + l15) * XS_STRIDE + ks * 32 + q * 8]);
            bf16x8 xa = ks ? xf1 : xf0;
            e0 = MFMA(xa, wc0, e0);
            e1 = MFMA(xa, wc1, e1);
        }
        unsigned short* ecw = &ecs[w * 16 * EC_STRIDE];
        #pragma unroll
        for (int r = 0; r < 4; ++r) {
            int row = q * 4 + r;           // C/D: row = quad*4 + reg
            union { bf16x2 v; unsigned short u[2]; } pr;
            pr.v = cvt2(fmaxf(e0[r], 0.f), fmaxf(e1[r], 0.f));
            ecw[row * EC_STRIDE + l15]      = pr.u[0];
            ecw[row * EC_STRIDE + 16 + l15] = pr.u[1];
        }
    }

    // ---- ec A-frag (wave-private; compiler inserts lgkmcnt wait) ----
    bf16x8 ecfrag = *reinterpret_cast<const bf16x8*>(
        &ecs[(w * 16 + l15) * EC_STRIDE + q * 8]);

    // ---- g-loop: enc_feature + logits + unnormalized softmax partials ----
    for (int g = 0; g < 8; ++g) {
        bf16x8 wf0 = *reinterpret_cast<const bf16x8*>(
            &ws[WS_WF + (g * 16 + l15) * XS_STRIDE + q * 8]);
        bf16x8 wf1 = *reinterpret_cast<const bf16x8*>(
            &ws[WS_WF + (g * 16 + l15) * XS_STRIDE + 32 + q * 8]);
        bf16x8 wag = *reinterpret_cast<const bf16x8*>(
            &ws[WS_WA + (g * 16 + l15) * WA_STRIDE + q * 8]);
        float bfl = bfv[g * 16 + l15];

        f32x4 z = {bfl, bfl, bfl, bfl};
        z = MFMA(xf0, wf0, z);
        f32x4 ef = MFMA(xf1, wf1, z);
        f32x4 zz = {0.f, 0.f, 0.f, 0.f};
        f32x4 lg = MFMA(ecfrag, wag, zz);

        float num = 0.f, den = 0.f;
        #pragma unroll
        for (int r = 0; r < 4; ++r) {
            float e = fmaxf(ef[r], 0.f);
            float pe = exp2f(lg[r]);       // log2e pre-folded into Wa
            num += pe * e;
            den += pe;
        }
        num += __shfl_xor(num, 16, 64); num += __shfl_xor(num, 32, 64);
        den += __shfl_xor(den, 16, 64); den += __shfl_xor(den, 32, 64);
        if (lane < 16) {
            aggnum[w][g * 16 + lane] = num;
            aggden[w][g * 16 + lane] = den;
        }
    }
    __syncthreads();

    // ---- block combine -> device atomics (num | den) ----
    if (tid < 128) {
        float v = aggnum[0][tid] + aggnum[1][tid] + aggnum[2][tid] + aggnum[3][tid];
        atomicAdd(&numden[(size_t)b * 256 + tid], v);
    } else {
        int k = tid - 128;
        float v = aggden[0][k] + aggden[1][k] + aggden[2][k] + aggden[3][k];
        atomicAdd(&numden[(size_t)b * 256 + 128 + k], v);
    }
}

// 512 blocks x 256 thr: block handles 2 batch rows; out = relu((num/den)@Wl + bl)
__global__ __launch_bounds__(256) void finish_kernel(
    const float* __restrict__ numden,   // [B][256]
    const unsigned short* __restrict__ ws,
    const float* __restrict__ blv,      // bl [128]
    float* __restrict__ out)            // [B][128]
{
    __shared__ float agg_s[2][LATD];
    const int tid = threadIdx.x;
    const int b0  = blockIdx.x * 2;

    {
        int lb = tid >> 7, k = tid & 127;
        const float* nd = numden + (size_t)(b0 + lb) * 256;
        agg_s[lb][k] = nd[k] / nd[128 + k];
    }
    __syncthreads();

    const float* wlt = reinterpret_cast<const float*>(
        reinterpret_cast<const char*>(ws) + WS_WLT_BYTES);
    int lb = tid >> 7, c = tid & 127;
    const float* wr = wlt + c * 128;
    float acc = blv[c];
    #pragma unroll
    for (int j = 0; j < 32; ++j) {
        float4 v = *reinterpret_cast<const float4*>(wr + j * 4);
        int k = j * 4;
        acc += agg_s[lb][k] * v.x + agg_s[lb][k + 1] * v.y +
               agg_s[lb][k + 2] * v.z + agg_s[lb][k + 3] * v.w;
    }
    out[(size_t)(b0 + lb) * LATD + c] = fmaxf(acc, 0.f);
}

extern "C" void kernel_launch(void* const* d_in, const int* in_sizes, int n_in,
                              void* d_out, int out_size, void* d_ws, size_t ws_size,
                              hipStream_t stream)
{
    const float* xg  = (const float*)d_in[1];
    const float* wc  = (const float*)d_in[2];
    const float* bc_ = (const float*)d_in[3];
    const float* wf  = (const float*)d_in[4];
    const float* bf_ = (const float*)d_in[5];
    const float* wa  = (const float*)d_in[6];
    const float* wl  = (const float*)d_in[8];
    const float* bl_ = (const float*)d_in[9];
    unsigned short* wsp = (unsigned short*)d_ws;   // needs WS_TOTAL_BYTES (~1.15 MB)
    float* numden = reinterpret_cast<float*>(reinterpret_cast<char*>(d_ws) + WS_ND_BYTES);
    float* out = (float*)d_out;

    hipMemsetAsync(numden, 0, 1024 * 256 * sizeof(float), stream);
    prep_kernel<<<16, 256, 0, stream>>>(wc, wf, wa, wl, wsp);
    encode_kernel<<<4096, 256, 0, stream>>>(xg, bc_, bf_, wsp, numden);
    finish_kernel<<<512, 256, 0, stream>>>(numden, wsp, bl_, out);
}